// Round 1
// baseline (37.635 us; speedup 1.0000x reference)
//
#include <hip/hip_runtime.h>

// Problem: B=16, H=256, W=256, D=256
//   loss = mean over (b,h,w) of (rec[b,h,w,idx[b]] - in2d[b,h,w])^2
#define HWB   65536      // H*W = 256*256
#define DDIM  256
#define NTOT  1048576    // B*H*W

__global__ __launch_bounds__(256) void pjc_main_kernel(
    const float* __restrict__ rec,
    const float* __restrict__ in2d,
    const int*   __restrict__ sidx,
    float*       __restrict__ ws_accum)
{
    // 262144 threads total; each handles 4 consecutive (h,w) elements.
    int gid = blockIdx.x * 256 + threadIdx.x;   // 0 .. 262143
    int i   = gid << 2;                          // flat element index (b*HWB + h*W + w)
    int b      = i >> 16;                        // / 65536  (uniform per block)
    int within = i & 65535;

    int d = sidx[b];

    // coalesced 16B load of input_2d
    const float4 in4 = *reinterpret_cast<const float4*>(in2d + i);

    // 4 gathers at stride D*4 = 1024 B (one cache line each — unavoidable)
    const float* base = rec + (((size_t)b << 16) + (size_t)within) * (size_t)DDIM + d;
    float r0 = base[0 * DDIM];
    float r1 = base[1 * DDIM];
    float r2 = base[2 * DDIM];
    float r3 = base[3 * DDIM];

    float d0 = r0 - in4.x;
    float d1 = r1 - in4.y;
    float d2 = r2 - in4.z;
    float d3 = r3 - in4.w;
    float local = d0 * d0 + d1 * d1 + d2 * d2 + d3 * d3;

    // wave-64 butterfly reduce
    #pragma unroll
    for (int off = 32; off > 0; off >>= 1)
        local += __shfl_down(local, off);

    __shared__ float wsum[4];
    int lane = threadIdx.x & 63;
    int wid  = threadIdx.x >> 6;
    if (lane == 0) wsum[wid] = local;
    __syncthreads();

    if (threadIdx.x == 0) {
        float s = wsum[0] + wsum[1] + wsum[2] + wsum[3];
        atomicAdd(ws_accum, s);   // device-scope by default on CDNA
    }
}

__global__ void pjc_final_kernel(const float* __restrict__ ws_accum,
                                 float* __restrict__ out)
{
    out[0] = ws_accum[0] * (1.0f / (float)NTOT);
}

extern "C" void kernel_launch(void* const* d_in, const int* in_sizes, int n_in,
                              void* d_out, int out_size, void* d_ws, size_t ws_size,
                              hipStream_t stream) {
    const float* rec  = (const float*)d_in[0];   // [16,256,256,256] f32
    const float* in2d = (const float*)d_in[1];   // [16,256,256]     f32
    const int*   sidx = (const int*)d_in[2];     // [16]             int
    float* out = (float*)d_out;                  // scalar f32
    float* ws  = (float*)d_ws;

    // zero the accumulator every launch (graph-capture safe)
    hipMemsetAsync(ws, 0, sizeof(float), stream);

    // 1024 blocks * 256 threads * 4 elems = 1,048,576 = NTOT exactly
    pjc_main_kernel<<<1024, 256, 0, stream>>>(rec, in2d, sidx, ws);
    pjc_final_kernel<<<1, 1, 0, stream>>>(ws, out);
}

// Round 2
// 27.344 us; speedup vs baseline: 1.3763x; 1.3763x over previous
//
#include <hip/hip_runtime.h>

// Problem: B=16, H=256, W=256, D=256
//   loss = mean over (b,h,w) of (rec[b,h,w,idx[b]] - in2d[b,h,w])^2
#define HWB    65536      // H*W
#define DDIM   256
#define NTOT   1048576    // B*H*W
#define NBLK   2048       // main-kernel blocks; 512 elements per block

// Each block handles 512 consecutive flat elements (entirely within one batch,
// since 512 | 65536). Lane l handles elements base+tid and base+256+tid:
// consecutive hw across lanes -> per-instruction gather span = 64 KiB.
__global__ __launch_bounds__(256) void pjc_main_kernel(
    const float* __restrict__ rec,
    const float* __restrict__ in2d,
    const int*   __restrict__ sidx,
    float*       __restrict__ partial)
{
    const int tid  = threadIdx.x;
    const int base = blockIdx.x << 9;          // first flat element (b*HWB + hw)
    const int b    = base >> 16;               // uniform per block
    const int d    = sidx[b];

    const float* __restrict__ recd = rec + d;  // rec[..., d] base

    const int i0 = base + tid;
    const int i1 = base + 256 + tid;

    // gathers: stride 1 KiB across lanes (one line each — intrinsic cost)
    float r0 = recd[(size_t)i0 << 8];
    float r1 = recd[(size_t)i1 << 8];
    // coalesced in2d reads (64 lanes x 4 B contiguous per wave)
    float x0 = in2d[i0];
    float x1 = in2d[i1];

    float d0 = r0 - x0;
    float d1 = r1 - x1;
    float acc = d0 * d0 + d1 * d1;

    // wave-64 butterfly reduce
    #pragma unroll
    for (int off = 32; off > 0; off >>= 1)
        acc += __shfl_down(acc, off);

    __shared__ float wsum[4];
    if ((tid & 63) == 0) wsum[tid >> 6] = acc;
    __syncthreads();

    if (tid == 0)
        partial[blockIdx.x] = wsum[0] + wsum[1] + wsum[2] + wsum[3];
}

// Reduce NBLK partials -> scalar mean. One block, 1024 threads.
__global__ __launch_bounds__(1024) void pjc_final_kernel(
    const float* __restrict__ partial,
    float*       __restrict__ out)
{
    const int tid = threadIdx.x;
    float s = partial[tid] + partial[tid + 1024];

    #pragma unroll
    for (int off = 32; off > 0; off >>= 1)
        s += __shfl_down(s, off);

    __shared__ float wsum[16];
    if ((tid & 63) == 0) wsum[tid >> 6] = s;
    __syncthreads();

    if (tid == 0) {
        float t = 0.f;
        #pragma unroll
        for (int i = 0; i < 16; ++i) t += wsum[i];
        out[0] = t * (1.0f / (float)NTOT);
    }
}

extern "C" void kernel_launch(void* const* d_in, const int* in_sizes, int n_in,
                              void* d_out, int out_size, void* d_ws, size_t ws_size,
                              hipStream_t stream) {
    const float* rec  = (const float*)d_in[0];   // [16,256,256,256] f32
    const float* in2d = (const float*)d_in[1];   // [16,256,256]     f32
    const int*   sidx = (const int*)d_in[2];     // [16]             int32
    float* out = (float*)d_out;                  // scalar f32
    float* ws  = (float*)d_ws;                   // >= NBLK floats (8 KiB)

    // partials are written unconditionally -> no memset needed
    pjc_main_kernel<<<NBLK, 256, 0, stream>>>(rec, in2d, sidx, ws);
    pjc_final_kernel<<<1, 1024, 0, stream>>>(ws, out);
}